// Round 2
// baseline (695.704 us; speedup 1.0000x reference)
//
#include <hip/hip_runtime.h>
#include <hip/hip_bf16.h>
#include <stdint.h>
#include <stddef.h>

#define BATCH 512
#define RSZ   196
#define DV    1024
#define DH    512
#define DA    256
#define MTOT  (BATCH * RSZ)   // 100352 = 128 * 784

typedef short short8 __attribute__((ext_vector_type(8)));
typedef float f32x4 __attribute__((ext_vector_type(4)));

static __device__ __forceinline__ short f2bf(float f) {
    union { float f; unsigned u; } x; x.f = f;
    unsigned r = x.u + 0x7fffu + ((x.u >> 16) & 1u);  // RNE
    return (short)(r >> 16);
}

// packed fp32x2 -> bf16x2 (v_cvt_pk_bf16_f32 on gfx950), returned as int
static __device__ __forceinline__ int pk2(float x, float y) {
    float2 f; f.x = x; f.y = y;
    __hip_bfloat162 h = __float22bfloat162_rn(f);
    int r; __builtin_memcpy(&r, &h, 4); return r;
}

static __device__ __forceinline__ void gl_lds16(const short* g, short* s) {
    __builtin_amdgcn_global_load_lds(
        (const __attribute__((address_space(1))) void*)g,
        (__attribute__((address_space(3))) void*)s, 16, 0, 0);
}

// ---------------- kernel 0: fused prep
//  blocks [0,64):   Wv [1024][256] fp32 -> WvT [256][1024] bf16 (16 k-rows per block)
//  blocks [64,576): H[b][a] = hs[b]@Wh[:,a] + bh[a] + bv[a]
__global__ __launch_bounds__(256) void k_prep(const float* __restrict__ Wv,
                                              const float* __restrict__ hs,
                                              const float* __restrict__ Wh,
                                              const float* __restrict__ bh,
                                              const float* __restrict__ bv,
                                              short* __restrict__ WvT,
                                              float* __restrict__ H) {
    int tid = threadIdx.x;
    if (blockIdx.x < 64) {
        __shared__ short tile[16][DA];
        int k0 = blockIdx.x * 16;
#pragma unroll
        for (int r = 0; r < 16; ++r)
            tile[r][tid] = f2bf(Wv[(size_t)(k0 + r) * DA + tid]);
        __syncthreads();
        short o[16];
#pragma unroll
        for (int r = 0; r < 16; ++r) o[r] = tile[r][tid];
        *(short8*)&WvT[(size_t)tid * DV + k0]     = *(short8*)&o[0];
        *(short8*)&WvT[(size_t)tid * DV + k0 + 8] = *(short8*)&o[8];
    } else {
        __shared__ float sh[DH];
        int b = blockIdx.x - 64, a = tid;
        sh[a]       = hs[b * DH + a];
        sh[a + 256] = hs[b * DH + 256 + a];
        __syncthreads();
        float acc = 0.f;
#pragma unroll 8
        for (int k = 0; k < DH; ++k) acc += sh[k] * Wh[k * DA + a];
        H[b * DA + a] = acc + bh[a] + bv[a];
    }
}

// ---------------- kernel 1: fused v_proj GEMM (bf16 MFMA) + relu + dot(Wa) -> scores
#define BM  128
#define BN  256
#define BK  64
#define LDA 72

__global__ __launch_bounds__(256, 2) void k_scores(const float* __restrict__ vf,
                                                   const short* __restrict__ WvT,
                                                   const float* __restrict__ H,
                                                   const float* __restrict__ Wa,
                                                   const float* __restrict__ ba,
                                                   float* __restrict__ scores) {
    __shared__ short As[BM * LDA];    // 18 KB, padded
    __shared__ short Bs[BN * BK];     // 32 KB, unpadded + XOR-swizzled (global_load_lds dest)
    __shared__ float sWa[DA];
    __shared__ float sH[2][DA];
    __shared__ float red[BM][4];

    const int tid = threadIdx.x;
    const int l   = tid & 63;
    const int w   = tid >> 6;          // wave 0..3 -> N-chunk w*64
    const int ln  = l & 15;
    const int q   = l >> 4;            // quad 0..3
    const int m0  = blockIdx.x * BM;
    const int b0  = m0 / RSZ;
    const int bL  = (m0 + BM - 1) / RSZ;   // at most b0+1 (BM < RSZ)

    sWa[tid]   = Wa[tid];
    sH[0][tid] = H[b0 * DA + tid];
    sH[1][tid] = H[bL * DA + tid];

    f32x4 acc[8][4];
#pragma unroll
    for (int i = 0; i < 8; ++i)
#pragma unroll
        for (int j = 0; j < 4; ++j) acc[i][j] = (f32x4){0.f, 0.f, 0.f, 0.f};

    // A staging: thread -> row ar, 32 cols at ac
    const int ar = tid >> 1;           // 0..127
    const int ac = (tid & 1) * 32;     // 0 / 32
    const float4* ap = (const float4*)(vf + (size_t)(m0 + ar) * DV + ac);
    short* awr = &As[ar * LDA + ac];

    // B staging via global_load_lds: wave w loads its own rows [w*64, w*64+64)
    // LDS chunk (n, c) holds global chunk (n, c ^ (n&7)); inst j covers rows w*64+j*8 .. +8
    const int g   = l >> 3;            // 0..7 : row within 8-row group
    const int c   = l & 7;             // 0..7 : 16B chunk slot
    const int csw = c ^ g;             // swizzled source chunk
    const short* bsrc = WvT + (size_t)(w * 64 + g) * DV + csw * 8;
    short* bdst = &Bs[(w * 8) * 512];  // 512 shorts (1 KB) per instruction

    for (int kt = 0; kt < DV; kt += BK) {
        // ---- B async (8 x 1KB per wave)
#pragma unroll
        for (int j = 0; j < 8; ++j)
            gl_lds16(bsrc + (size_t)j * 8 * DV + kt, bdst + j * 512);
        // ---- A: 32 fp32 -> bf16 per thread
        int kb = kt >> 2;
        float4 f0 = ap[kb + 0], f1 = ap[kb + 1], f2 = ap[kb + 2], f3 = ap[kb + 3];
        float4 f4 = ap[kb + 4], f5 = ap[kb + 5], f6 = ap[kb + 6], f7 = ap[kb + 7];
        union { short8 v; int i[4]; } u0, u1, u2, u3;
        u0.i[0] = pk2(f0.x, f0.y); u0.i[1] = pk2(f0.z, f0.w);
        u0.i[2] = pk2(f1.x, f1.y); u0.i[3] = pk2(f1.z, f1.w);
        u1.i[0] = pk2(f2.x, f2.y); u1.i[1] = pk2(f2.z, f2.w);
        u1.i[2] = pk2(f3.x, f3.y); u1.i[3] = pk2(f3.z, f3.w);
        u2.i[0] = pk2(f4.x, f4.y); u2.i[1] = pk2(f4.z, f4.w);
        u2.i[2] = pk2(f5.x, f5.y); u2.i[3] = pk2(f5.z, f5.w);
        u3.i[0] = pk2(f6.x, f6.y); u3.i[1] = pk2(f6.z, f6.w);
        u3.i[2] = pk2(f7.x, f7.y); u3.i[3] = pk2(f7.z, f7.w);
        *(short8*)&awr[0]  = u0.v;
        *(short8*)&awr[8]  = u1.v;
        *(short8*)&awr[16] = u2.v;
        *(short8*)&awr[24] = u3.v;
        __syncthreads();   // drains vmcnt (global_load_lds) + lgkm
#pragma unroll
        for (int kk = 0; kk < 2; ++kk) {
            short8 bfr[4];
#pragma unroll
            for (int j = 0; j < 4; ++j) {
                int n = w * 64 + j * 16 + ln;
                bfr[j] = *(short8*)&Bs[n * BK + ((4 * kk + q) ^ (ln & 7)) * 8];
            }
#pragma unroll
            for (int i = 0; i < 8; ++i) {
                short8 afr = *(short8*)&As[(i * 16 + ln) * LDA + kk * 32 + q * 8];
#pragma unroll
                for (int j = 0; j < 4; ++j)
                    acc[i][j] = __builtin_amdgcn_mfma_f32_16x16x32_bf16(
                        afr, bfr[j], acc[i][j], 0, 0, 0);
            }
        }
        __syncthreads();
    }

    // ---- epilogue: relu(acc + H) * Wa, reduce over 256 cols
#pragma unroll
    for (int i = 0; i < 8; ++i) {
#pragma unroll
        for (int r = 0; r < 4; ++r) {
            int row = i * 16 + q * 4 + r;
            int bb  = (unsigned)(m0 + row) / RSZ;
            const float* hrow = sH[bb - b0];
            float p = 0.f;
#pragma unroll
            for (int j = 0; j < 4; ++j) {
                int a   = w * 64 + j * 16 + ln;
                float v = acc[i][j][r] + hrow[a];
                p += fmaxf(v, 0.f) * sWa[a];
            }
            p += __shfl_xor(p, 1);
            p += __shfl_xor(p, 2);
            p += __shfl_xor(p, 4);
            p += __shfl_xor(p, 8);
            if (ln == 0) red[row][w] = p;
        }
    }
    __syncthreads();
    if (tid < BM) {
        scores[m0 + tid] = red[tid][0] + red[tid][1] + red[tid][2] + red[tid][3] + ba[0];
    }
}

// ---------------- kernel 2: fused softmax + att@vf  (one block per batch)
__global__ __launch_bounds__(256) void k_out(const float* __restrict__ vf,
                                             const float* __restrict__ scores,
                                             float* __restrict__ out) {
    __shared__ float satt[RSZ];
    __shared__ float wrm[4];
    __shared__ float wrs[4];
    const int b = blockIdx.x, t = threadIdx.x;
    const int l = t & 63, w = t >> 6;

    float v = (t < RSZ) ? scores[b * RSZ + t] : -1e30f;
    float m = v;
#pragma unroll
    for (int mk = 32; mk >= 1; mk >>= 1) m = fmaxf(m, __shfl_xor(m, mk));
    if (l == 0) wrm[w] = m;
    __syncthreads();
    m = fmaxf(fmaxf(wrm[0], wrm[1]), fmaxf(wrm[2], wrm[3]));
    float e = (t < RSZ) ? expf(v - m) : 0.f;
    float s = e;
#pragma unroll
    for (int mk = 32; mk >= 1; mk >>= 1) s += __shfl_xor(s, mk);
    if (l == 0) wrs[w] = s;
    __syncthreads();
    s = wrs[0] + wrs[1] + wrs[2] + wrs[3];
    if (t < RSZ) satt[t] = e / s;
    __syncthreads();

    const float4* vp = (const float4*)(vf + (size_t)b * RSZ * DV) + t;  // cols 4t..4t+3
    float4 acc = {0.f, 0.f, 0.f, 0.f};
    for (int r = 0; r < RSZ; r += 4) {   // 196 = 4*49
        float4 v0 = vp[(r + 0) * (DV / 4)];
        float4 v1 = vp[(r + 1) * (DV / 4)];
        float4 v2 = vp[(r + 2) * (DV / 4)];
        float4 v3 = vp[(r + 3) * (DV / 4)];
        float a0 = satt[r], a1 = satt[r + 1], a2 = satt[r + 2], a3 = satt[r + 3];
        acc.x += a0 * v0.x + a1 * v1.x + a2 * v2.x + a3 * v3.x;
        acc.y += a0 * v0.y + a1 * v1.y + a2 * v2.y + a3 * v3.y;
        acc.z += a0 * v0.z + a1 * v1.z + a2 * v2.z + a3 * v3.z;
        acc.w += a0 * v0.w + a1 * v1.w + a2 * v2.w + a3 * v3.w;
    }
    ((float4*)(out + (size_t)b * DV))[t] = acc;
}

extern "C" void kernel_launch(void* const* d_in, const int* in_sizes, int n_in,
                              void* d_out, int out_size, void* d_ws, size_t ws_size,
                              hipStream_t stream) {
    const float* vf = (const float*)d_in[0];   // [512,196,1024]
    const float* hs = (const float*)d_in[1];   // [512,512]
    const float* Wv = (const float*)d_in[2];   // [1024,256]
    const float* bv = (const float*)d_in[3];   // [256]
    const float* Wh = (const float*)d_in[4];   // [512,256]
    const float* bh = (const float*)d_in[5];   // [256]
    const float* Wa = (const float*)d_in[6];   // [256]
    const float* ba = (const float*)d_in[7];   // scalar
    float* out = (float*)d_out;                // [512,1024]

    char* ws = (char*)d_ws;
    short* WvT    = (short*)(ws);                       // 512 KB
    float* H      = (float*)(ws + (512 << 10));         // 512 KB
    float* scores = (float*)(ws + (1024 << 10));        // 392 KB

    k_prep<<<576, 256, 0, stream>>>(Wv, hs, Wh, bh, bv, WvT, H);
    k_scores<<<MTOT / BM, 256, 0, stream>>>(vf, WvT, H, Wa, ba, scores);
    k_out<<<BATCH, 256, 0, stream>>>(vf, scores, out);
}

// Round 3
// 653.216 us; speedup vs baseline: 1.0650x; 1.0650x over previous
//
#include <hip/hip_runtime.h>
#include <hip/hip_bf16.h>
#include <stdint.h>
#include <stddef.h>

#define BATCH 512
#define RSZ   196
#define DV    1024
#define DH    512
#define DA    256

typedef short short8 __attribute__((ext_vector_type(8)));
typedef float f32x4 __attribute__((ext_vector_type(4)));

static __device__ __forceinline__ short f2bf(float f) {
    union { float f; unsigned u; } x; x.f = f;
    unsigned r = x.u + 0x7fffu + ((x.u >> 16) & 1u);  // RNE
    return (short)(r >> 16);
}

// packed fp32x2 -> bf16x2 (v_cvt_pk_bf16_f32 on gfx950), returned as int
static __device__ __forceinline__ int pk2(float x, float y) {
    float2 f; f.x = x; f.y = y;
    __hip_bfloat162 h = __float22bfloat162_rn(f);
    int r; __builtin_memcpy(&r, &h, 4); return r;
}

static __device__ __forceinline__ void gl_lds16(const short* g, short* s) {
    __builtin_amdgcn_global_load_lds(
        (const __attribute__((address_space(1))) void*)g,
        (__attribute__((address_space(3))) void*)s, 16, 0, 0);
}

// ---------------- kernel 0: fused prep
//  blocks [0,64):   Wv [1024][256] fp32 -> WvT [256][1024] bf16 (16 k-rows per block)
//  blocks [64,576): H[b][a] = hs[b]@Wh[:,a] + bh[a] + bv[a]
__global__ __launch_bounds__(256) void k_prep(const float* __restrict__ Wv,
                                              const float* __restrict__ hs,
                                              const float* __restrict__ Wh,
                                              const float* __restrict__ bh,
                                              const float* __restrict__ bv,
                                              short* __restrict__ WvT,
                                              float* __restrict__ H) {
    int tid = threadIdx.x;
    if (blockIdx.x < 64) {
        __shared__ short tile[16][DA];
        int k0 = blockIdx.x * 16;
#pragma unroll
        for (int r = 0; r < 16; ++r)
            tile[r][tid] = f2bf(Wv[(size_t)(k0 + r) * DA + tid]);
        __syncthreads();
        short o[16];
#pragma unroll
        for (int r = 0; r < 16; ++r) o[r] = tile[r][tid];
        *(short8*)&WvT[(size_t)tid * DV + k0]     = *(short8*)&o[0];
        *(short8*)&WvT[(size_t)tid * DV + k0 + 8] = *(short8*)&o[8];
    } else {
        __shared__ float sh[DH];
        int b = blockIdx.x - 64, a = tid;
        sh[a]       = hs[b * DH + a];
        sh[a + 256] = hs[b * DH + 256 + a];
        __syncthreads();
        float acc = 0.f;
#pragma unroll 8
        for (int k = 0; k < DH; ++k) acc += sh[k] * Wh[k * DA + a];
        H[b * DA + a] = acc + bh[a] + bv[a];
    }
}

// ---------------- kernel 1: fully-fused flash-style attention
// One block per batch. For each M-tile of rows: bf16 MFMA scores -> online
// softmax -> out-accumulate with fp32 vf (L2/L3-hot re-read).
#define BK  64
#define LDA 72

__global__ __launch_bounds__(256, 2) void k_fused(const float* __restrict__ vf,
                                                  const short* __restrict__ WvT,
                                                  const float* __restrict__ H,
                                                  const float* __restrict__ Wa,
                                                  const float* __restrict__ ba,
                                                  float* __restrict__ out) {
    __shared__ short As[64 * LDA];     // 9 KB (padded, ds_write staged)
    __shared__ short Bs[DA * BK];      // 32 KB (global_load_lds dest, XOR-swizzled)
    __shared__ float sH[DA];
    __shared__ float sWa[DA];
    __shared__ float red[64][4];
    __shared__ float sp[64];           // tile p-values
    __shared__ float sml[4];           // [0]=running m, [1]=running l, [2]=alpha

    const int tid = threadIdx.x;
    const int l   = tid & 63;
    const int w   = tid >> 6;          // wave 0..3 -> N-chunk w*64
    const int ln  = l & 15;
    const int q   = l >> 4;
    const int b   = blockIdx.x;

    sH[tid]  = H[b * DA + tid];
    sWa[tid] = Wa[tid];
    if (tid == 0) { sml[0] = -1e30f; sml[1] = 0.f; }

    // A staging: thread -> row ar (0..63), 16 cols at ac
    const int ar = tid >> 2;
    const int ac = (tid & 3) * 16;

    // B staging via global_load_lds (verified swizzle from round 2):
    // LDS chunk (n, c) holds global chunk (n, c ^ (n&7))
    const int g   = l >> 3;
    const int c   = l & 7;
    const int csw = c ^ g;
    const short* bsrc = WvT + (size_t)(w * 64 + g) * DV + csw * 8;
    short* bdst = &Bs[(w * 8) * 512];

    float4 O = {0.f, 0.f, 0.f, 0.f};   // each thread owns cols 4*tid..4*tid+3
    const float baS = ba[0];

    __syncthreads();

    for (int t = 0; t < 4; ++t) {
        const int r0    = t * 64;
        const int nrows = (t < 3) ? 64 : (RSZ - 192);   // 64,64,64,4
        const int micnt = (t < 3) ? 4 : 1;
        const bool rok  = (ar < nrows);
        const float4* ap = (const float4*)(vf + ((size_t)b * RSZ + r0 + (rok ? ar : 0)) * DV + ac);
        short* awr = &As[ar * LDA + ac];

        f32x4 acc[4][4];
#pragma unroll
        for (int i = 0; i < 4; ++i)
#pragma unroll
            for (int j = 0; j < 4; ++j) acc[i][j] = (f32x4){0.f, 0.f, 0.f, 0.f};

        for (int kt = 0; kt < DV; kt += BK) {
            // ---- B async (8 x 1KB per wave)
#pragma unroll
            for (int j = 0; j < 8; ++j)
                gl_lds16(bsrc + (size_t)j * 8 * DV + kt, bdst + j * 512);
            // ---- A: 16 fp32 -> bf16 per thread
            int kb = kt >> 2;
            float4 f0, f1, f2, f3;
            if (rok) { f0 = ap[kb]; f1 = ap[kb + 1]; f2 = ap[kb + 2]; f3 = ap[kb + 3]; }
            else     { f0 = f1 = f2 = f3 = (float4){0.f, 0.f, 0.f, 0.f}; }
            union { short8 v; int i[4]; } u0, u1;
            u0.i[0] = pk2(f0.x, f0.y); u0.i[1] = pk2(f0.z, f0.w);
            u0.i[2] = pk2(f1.x, f1.y); u0.i[3] = pk2(f1.z, f1.w);
            u1.i[0] = pk2(f2.x, f2.y); u1.i[1] = pk2(f2.z, f2.w);
            u1.i[2] = pk2(f3.x, f3.y); u1.i[3] = pk2(f3.z, f3.w);
            *(short8*)&awr[0] = u0.v;
            *(short8*)&awr[8] = u1.v;
            __syncthreads();
#pragma unroll
            for (int kk = 0; kk < 2; ++kk) {
                short8 bfr[4];
#pragma unroll
                for (int j = 0; j < 4; ++j) {
                    int n = w * 64 + j * 16 + ln;
                    bfr[j] = *(short8*)&Bs[n * BK + ((4 * kk + q) ^ (ln & 7)) * 8];
                }
#pragma unroll
                for (int i = 0; i < 4; ++i) {
                    if (i < micnt) {
                        short8 afr = *(short8*)&As[(i * 16 + ln) * LDA + kk * 32 + q * 8];
#pragma unroll
                        for (int j = 0; j < 4; ++j)
                            acc[i][j] = __builtin_amdgcn_mfma_f32_16x16x32_bf16(
                                afr, bfr[j], acc[i][j], 0, 0, 0);
                    }
                }
            }
            __syncthreads();
        }

        // ---- epilogue: relu(acc + H) * Wa, reduce over 256 cols -> red[row][w]
#pragma unroll
        for (int i = 0; i < 4; ++i) {
            if (i < micnt) {
#pragma unroll
                for (int r = 0; r < 4; ++r) {
                    int row = i * 16 + q * 4 + r;
                    float p = 0.f;
#pragma unroll
                    for (int j = 0; j < 4; ++j) {
                        int a   = w * 64 + j * 16 + ln;
                        float v = acc[i][j][r] + sH[a];
                        p += fmaxf(v, 0.f) * sWa[a];
                    }
                    p += __shfl_xor(p, 1);
                    p += __shfl_xor(p, 2);
                    p += __shfl_xor(p, 4);
                    p += __shfl_xor(p, 8);
                    if (ln == 0) red[row][w] = p;
                }
            }
        }
        __syncthreads();

        // ---- online softmax update (wave 0)
        if (tid < 64) {
            float s = (tid < nrows)
                    ? (red[tid][0] + red[tid][1] + red[tid][2] + red[tid][3] + baS)
                    : -1e30f;
            float tm = s;
#pragma unroll
            for (int mk = 32; mk >= 1; mk >>= 1) tm = fmaxf(tm, __shfl_xor(tm, mk));
            float m_old = sml[0];
            float m_new = fmaxf(m_old, tm);
            float p = (tid < nrows) ? expf(s - m_new) : 0.f;
            sp[tid] = p;
            float ls = p;
#pragma unroll
            for (int mk = 32; mk >= 1; mk >>= 1) ls += __shfl_xor(ls, mk);
            if (tid == 0) {
                float alpha = expf(m_old - m_new);
                sml[2] = alpha;
                sml[1] = sml[1] * alpha + ls;
                sml[0] = m_new;
            }
        }
        __syncthreads();

        // ---- out accumulate: O = O*alpha + sum_r p[r] * vf[r]  (fp32, L2/L3-hot)
        float alpha = sml[2];
        O.x *= alpha; O.y *= alpha; O.z *= alpha; O.w *= alpha;
        const float4* vrow = (const float4*)(vf + ((size_t)b * RSZ + r0) * DV) + tid;
        for (int r = 0; r + 3 < nrows; r += 4) {    // nrows is 64 or 4
            float4 v0 = vrow[(r + 0) * (DV / 4)];
            float4 v1 = vrow[(r + 1) * (DV / 4)];
            float4 v2 = vrow[(r + 2) * (DV / 4)];
            float4 v3 = vrow[(r + 3) * (DV / 4)];
            float p0 = sp[r], p1 = sp[r + 1], p2 = sp[r + 2], p3 = sp[r + 3];
            O.x += p0 * v0.x + p1 * v1.x + p2 * v2.x + p3 * v3.x;
            O.y += p0 * v0.y + p1 * v1.y + p2 * v2.y + p3 * v3.y;
            O.z += p0 * v0.z + p1 * v1.z + p2 * v2.z + p3 * v3.z;
            O.w += p0 * v0.w + p1 * v1.w + p2 * v2.w + p3 * v3.w;
        }
        // barrier before next tile re-stages As/Bs & wave0 rewrites sp/sml:
        // first K-iter __syncthreads() of next tile covers it (all threads
        // pass a barrier after reading sp and before any rewrite).
    }

    float invl = 1.f / sml[1];
    float4 res = {O.x * invl, O.y * invl, O.z * invl, O.w * invl};
    ((float4*)(out + (size_t)b * DV))[tid] = res;
}

extern "C" void kernel_launch(void* const* d_in, const int* in_sizes, int n_in,
                              void* d_out, int out_size, void* d_ws, size_t ws_size,
                              hipStream_t stream) {
    const float* vf = (const float*)d_in[0];   // [512,196,1024]
    const float* hs = (const float*)d_in[1];   // [512,512]
    const float* Wv = (const float*)d_in[2];   // [1024,256]
    const float* bv = (const float*)d_in[3];   // [256]
    const float* Wh = (const float*)d_in[4];   // [512,256]
    const float* bh = (const float*)d_in[5];   // [256]
    const float* Wa = (const float*)d_in[6];   // [256]
    const float* ba = (const float*)d_in[7];   // scalar
    float* out = (float*)d_out;                // [512,1024]

    char* ws = (char*)d_ws;
    short* WvT = (short*)(ws);                 // 512 KB
    float* H   = (float*)(ws + (512 << 10));   // 512 KB

    k_prep<<<576, 256, 0, stream>>>(Wv, hs, Wh, bh, bv, WvT, H);
    k_fused<<<BATCH, 256, 0, stream>>>(vf, WvT, H, Wa, ba, out);
}